// Round 7
// baseline (822.291 us; speedup 1.0000x reference)
//
#include <hip/hip_runtime.h>
#include <stdint.h>

// BitNet b1.58 column-parallel linear:
//   y[m,n] = (sum_k qx[m,k]*qw[n,k]) * inv_sx[m] * inv_sw + bias[n]
// M=8192 (B*S), N=16384 (D_OUT), K=4096 (D_IN)

#define M_ROWS 8192
#define N_COLS 16384
#define K_DIM  4096
#define NT     (K_DIM / 64)   // 64 K-steps of 64 bytes

typedef int v4i __attribute__((ext_vector_type(4)));

// ---------------- workspace layout ----------------
#define WS_PARTIALS 0
#define WS_PARAMS   8192
#define WS_INVSX    8448
#define WS_QX       41216
#define WS_QW       (41216 + 33554432)
#define WS_NEED     ((size_t)WS_QW + 67108864)

// ---------------- activation quant: per-row int8 absmax ----------------
__device__ __forceinline__ int quant_act1(float v, float s) {
    float q = rintf(v * s);               // round-half-even, matches jnp.round
    q = fminf(127.0f, fmaxf(-128.0f, q));
    return (int)q;
}

__global__ __launch_bounds__(256) void act_quant_kernel(const float* __restrict__ x,
                                                        int8_t* __restrict__ qx,
                                                        float* __restrict__ inv_sx) {
    const int row = blockIdx.x;
    const int t = threadIdx.x;
    const float4* xr = (const float4*)(x + (size_t)row * K_DIM);

    float4 v[4];
    float m = 0.0f;
#pragma unroll
    for (int i = 0; i < 4; ++i) {
        v[i] = xr[t + 256 * i];
        m = fmaxf(m, fmaxf(fmaxf(fabsf(v[i].x), fabsf(v[i].y)),
                           fmaxf(fabsf(v[i].z), fabsf(v[i].w))));
    }
#pragma unroll
    for (int off = 32; off > 0; off >>= 1) m = fmaxf(m, __shfl_xor(m, off));
    __shared__ float wm[4];
    if ((t & 63) == 0) wm[t >> 6] = m;
    __syncthreads();
    m = fmaxf(fmaxf(wm[0], wm[1]), fmaxf(wm[2], wm[3]));
    m = fmaxf(m, 1e-5f);                  // clip(max, EPS)
    const float scale = 127.0f / m;
    if (t == 0) inv_sx[row] = 1.0f / scale;

    int* qr = (int*)(qx + (size_t)row * K_DIM);
#pragma unroll
    for (int i = 0; i < 4; ++i) {
        int b0 = quant_act1(v[i].x, scale) & 255;
        int b1 = quant_act1(v[i].y, scale) & 255;
        int b2 = quant_act1(v[i].z, scale) & 255;
        int b3 = quant_act1(v[i].w, scale) & 255;
        qr[t + 256 * i] = b0 | (b1 << 8) | (b2 << 16) | (b3 << 24);
    }
}

// ---------------- weight abs-sum (deterministic two-stage) ----------------
__global__ __launch_bounds__(256) void wabs_partial_kernel(const float* __restrict__ w,
                                                           float* __restrict__ partials) {
    const int t = threadIdx.x;
    const size_t base = (size_t)blockIdx.x * 8192;   // float4 units
    const float4* w4 = (const float4*)w;
    float s = 0.0f;
#pragma unroll 8
    for (int i = 0; i < 32; ++i) {
        float4 v = w4[base + (size_t)i * 256 + t];
        s += fabsf(v.x) + fabsf(v.y) + fabsf(v.z) + fabsf(v.w);
    }
#pragma unroll
    for (int off = 32; off > 0; off >>= 1) s += __shfl_xor(s, off);
    __shared__ float wp[4];
    if ((t & 63) == 0) wp[t >> 6] = s;
    __syncthreads();
    if (t == 0) partials[blockIdx.x] = (wp[0] + wp[1]) + (wp[2] + wp[3]);
}

__global__ __launch_bounds__(256) void wfinal_kernel(const float* __restrict__ partials,
                                                     float* __restrict__ params) {
    __shared__ double sh[256];
    const int t = threadIdx.x;
    double s = 0.0;
    for (int i = t; i < 2048; i += 256) s += (double)partials[i];
    sh[t] = s;
    __syncthreads();
    for (int off = 128; off > 0; off >>= 1) {
        if (t < off) sh[t] += sh[t + off];
        __syncthreads();
    }
    if (t == 0) {
        float mean = (float)(sh[0] / 67108864.0);
        mean = fmaxf(mean, 1e-5f);        // clip(mean, EPS)
        float scale = 1.0f / mean;        // scale_w
        params[0] = scale;
        params[1] = 1.0f / scale;         // inv_sw
    }
}

// ---------------- weight quant: per-tensor ternary ----------------
__device__ __forceinline__ int quant_w1(float v, float s) {
    float q = rintf(v * s);
    q = fminf(1.0f, fmaxf(-1.0f, q));
    return (int)q;
}

__global__ __launch_bounds__(256) void w_quant_kernel(const float* __restrict__ w,
                                                      int8_t* __restrict__ qw,
                                                      const float* __restrict__ params) {
    const float scale = params[0];
    const int stride = gridDim.x * 256;
    const float4* w4 = (const float4*)w;
    int* q4 = (int*)qw;
    for (int g = blockIdx.x * 256 + threadIdx.x; g < 16777216; g += stride) {
        float4 v = w4[g];
        int b0 = quant_w1(v.x, scale) & 255;
        int b1 = quant_w1(v.y, scale) & 255;
        int b2 = quant_w1(v.z, scale) & 255;
        int b3 = quant_w1(v.w, scale) & 255;
        q4[g] = b0 | (b1 << 8) | (b2 << 16) | (b3 << 24);
    }
}

// ---------------- int8 GEMM: 256x256 tile, 4 waves x (128x128)/wave, big-register ----
// Tensile-style geometry: 256 threads, 1 wave/SIMD, acc[8][8] (256 regs) per wave.
// Reads/MFMA = 16/64 per K-step (1.5x better intensity than 8-wave 128x64) ->
// per-CU LDS traffic (64KB rd + 32KB wr ~ 1130cy) < MFMA (1306cy): MFMA-bound.
// 4-slot ring (slot = ks&3, 32KB each: A 16KB + B 16KB), stage-3-ahead, 8 GLD/step.
// One vmcnt(16) + one s_barrier per K-step; read->MFMA deps left to the compiler's
// fine-grained lgkmcnt insertion (m97 evidence: it pipelines these well unfenced).
// 16B-chunk XOR swizzle on global source + ds_read addr (rounds 1-6: 0 conflicts).
__global__ __launch_bounds__(256, 1) void gemm_i8_kernel(const int8_t* __restrict__ qx,
                                                         const int8_t* __restrict__ qw,
                                                         const float* __restrict__ inv_sx,
                                                         const float* __restrict__ params,
                                                         const float* __restrict__ bias,
                                                         float* __restrict__ y) {
    __shared__ __align__(16) int8_t lds[4][32768];   // per slot: A[256][64] then B[256][64]
    int8_t* L = &lds[0][0];

    const int tid = threadIdx.x;
    const int lane = tid & 63;
    const int w = tid >> 6;           // wave 0..3
    const int wr = w >> 1;            // 0..1  (M half)
    const int wc = w & 1;             // 0..1  (N half)

    // XCD-aware bijective swizzle: 2048 blocks, 8 XCDs
    const int bid = blockIdx.x;
    const int swz = (bid & 7) * 256 + (bid >> 3);
    const int bn = swz & 63;          // 64 n-blocks
    const int bm = swz >> 6;          // 32 m-blocks

    const size_t arow0 = (size_t)bm * 256;
    const size_t brow0 = (size_t)bn * 256;

    // staging: per slot 2048 chunks of 16B (A 1024, B 1024); thread handles
    // chunks {tid+256g} of A and B. row = tid>>2 + 64g; k-slot XOR is g-invariant.
    const int r0 = tid >> 2;                       // 0..63
    const int kc0 = (tid & 3) ^ ((r0 >> 1) & 3);   // swizzled k-slot (involution)
    const int8_t* gA = qx + (arow0 + r0) * K_DIM + kc0 * 16;
    const int8_t* gB = qw + (brow0 + r0) * K_DIM + kc0 * 16;
    const int wgbase = w * 1024;                   // wave-uniform LDS staging base

#define GLD(g, l)                                                                        \
    __builtin_amdgcn_global_load_lds((const __attribute__((address_space(1))) void*)(g), \
                                     (__attribute__((address_space(3))) void*)(l), 16, 0, 0)

// stage K-step ks into slot S: 4 A-chunks + 4 B-chunks per thread (row stride 64)
#define GLD8(ks, S)                                                                      \
    do {                                                                                 \
        const size_t _o = (size_t)(ks) * 64;                                             \
        _Pragma("unroll") for (int _g = 0; _g < 4; ++_g)                                 \
            GLD(gA + _o + (size_t)_g * (64 * K_DIM),                                     \
                L + (S) * 32768 + wgbase + _g * 4096);                                   \
        _Pragma("unroll") for (int _g = 0; _g < 4; ++_g)                                 \
            GLD(gB + _o + (size_t)_g * (64 * K_DIM),                                     \
                L + (S) * 32768 + 16384 + wgbase + _g * 4096);                           \
    } while (0)

    // fragment ds_read offsets (within one slot) — verified 16x16x64 layout
    const int ksub = lane >> 4;       // 16B k-chunk 0..3
    const int lrow = lane & 15;
    int aoff[8], boff[8];
#pragma unroll
    for (int i = 0; i < 8; ++i) {
        int ra = wr * 128 + i * 16 + lrow;
        aoff[i] = ra * 64 + ((ksub ^ ((ra >> 1) & 3)) << 4);
        int rb = wc * 128 + i * 16 + lrow;
        boff[i] = 16384 + rb * 64 + ((ksub ^ ((rb >> 1) & 3)) << 4);
    }

    v4i acc[8][8];
#pragma unroll
    for (int i = 0; i < 8; ++i)
#pragma unroll
        for (int j = 0; j < 8; ++j) acc[i][j] = (v4i){0, 0, 0, 0};

#define BARR() __builtin_amdgcn_s_barrier()
#define VM(NSTR) asm volatile("s_waitcnt vmcnt(" NSTR ")" ::: "memory")

// One K-step: read 16 frags from slot CS, stage FKS->FSL (if STG), 64 MFMA,
// counted vmcnt, barrier (publishes slot CS+1; protects slot FSL-recycle).
#define STEP(CS, FKS, FSL, STG, VMSTR, DOBAR)                                  \
    do {                                                                       \
        const int8_t* _p = L + (CS) * 32768;                                   \
        v4i a[8], b[8];                                                        \
        _Pragma("unroll") for (int _i = 0; _i < 8; ++_i)                       \
            a[_i] = *(const v4i*)(_p + aoff[_i]);                              \
        _Pragma("unroll") for (int _j = 0; _j < 8; ++_j)                       \
            b[_j] = *(const v4i*)(_p + boff[_j]);                              \
        if (STG) GLD8(FKS, FSL);                                               \
        _Pragma("unroll") for (int _i = 0; _i < 8; ++_i)                       \
            _Pragma("unroll") for (int _j = 0; _j < 8; ++_j)                   \
                acc[_i][_j] = __builtin_amdgcn_mfma_i32_16x16x64_i8(           \
                    a[_i], b[_j], acc[_i][_j], 0, 0, 0);                       \
        VM(VMSTR);                                                             \
        if (DOBAR) BARR();                                                     \
    } while (0)

    // prologue: stage K-steps 0,1,2; vmcnt(16) proves K-step 0; barrier publishes
    GLD8(0, 0);
    GLD8(1, 1);
    GLD8(2, 2);
    VM("16");
    BARR();

    // main loop: j=0..14, K-steps 4j..4j+3, staging 4j+3..4j+6 (slots 3,0,1,2)
#pragma unroll 1
    for (int j = 0; j < 15; ++j) {
        const int tb = 4 * j;
        STEP(0, tb + 3, 3, 1, "16", 1);
        STEP(1, tb + 4, 0, 1, "16", 1);
        STEP(2, tb + 5, 1, 1, "16", 1);
        STEP(3, tb + 6, 2, 1, "16", 1);
    }
    // tail: t=60 stages 63; then drain 16 -> 8 -> 0 -> none
    STEP(0, 63, 3, 1, "16", 1);    // t=60: proves 61
    STEP(1, 0, 0, 0, "8", 1);      // t=61: proves 62
    STEP(2, 0, 0, 0, "0", 1);      // t=62: proves 63
    {                              // t=63: no wait, no barrier
        const int8_t* _p = L + 3 * 32768;
        v4i a[8], b[8];
#pragma unroll
        for (int _i = 0; _i < 8; ++_i) a[_i] = *(const v4i*)(_p + aoff[_i]);
#pragma unroll
        for (int _j = 0; _j < 8; ++_j) b[_j] = *(const v4i*)(_p + boff[_j]);
#pragma unroll
        for (int _i = 0; _i < 8; ++_i)
#pragma unroll
            for (int _j = 0; _j < 8; ++_j)
                acc[_i][_j] = __builtin_amdgcn_mfma_i32_16x16x64_i8(
                    a[_i], b[_j], acc[_i][_j], 0, 0, 0);
    }

    // epilogue: y = acc * inv_sx[row] * inv_sw + bias[col]  (verified 16x16 C/D layout)
    const float invsw = params[1];
    const int rl = (lane >> 4) * 4;
#pragma unroll
    for (int i = 0; i < 8; ++i) {
        const int grow_base = (int)arow0 + wr * 128 + i * 16 + rl;
        float isx[4];
#pragma unroll
        for (int r = 0; r < 4; ++r) isx[r] = inv_sx[grow_base + r] * invsw;
#pragma unroll
        for (int j = 0; j < 8; ++j) {
            const int gcol = (int)brow0 + wc * 128 + j * 16 + lrow;
            const float bb = bias[gcol];
#pragma unroll
            for (int r = 0; r < 4; ++r) {
                y[(size_t)(grow_base + r) * N_COLS + gcol] =
                    (float)acc[i][j][r] * isx[r] + bb;
            }
        }
    }
#undef GLD
#undef GLD8
#undef BARR
#undef VM
#undef STEP
}

// ---------------- launch ----------------
extern "C" void kernel_launch(void* const* d_in, const int* in_sizes, int n_in,
                              void* d_out, int out_size, void* d_ws, size_t ws_size,
                              hipStream_t stream) {
    const float* x    = (const float*)d_in[0];
    const float* wt   = (const float*)d_in[1];
    const float* bias = (const float*)d_in[2];
    float* y = (float*)d_out;

    if (ws_size < WS_NEED) return;

    char* ws = (char*)d_ws;
    float* partials = (float*)(ws + WS_PARTIALS);
    float* params   = (float*)(ws + WS_PARAMS);
    float* inv_sx   = (float*)(ws + WS_INVSX);
    int8_t* qx = (int8_t*)(ws + WS_QX);
    int8_t* qw = (int8_t*)(ws + WS_QW);

    hipLaunchKernelGGL(act_quant_kernel,   dim3(8192), dim3(256), 0, stream, x, qx, inv_sx);
    hipLaunchKernelGGL(wabs_partial_kernel,dim3(2048), dim3(256), 0, stream, wt, partials);
    hipLaunchKernelGGL(wfinal_kernel,      dim3(1),    dim3(256), 0, stream, partials, params);
    hipLaunchKernelGGL(w_quant_kernel,     dim3(4096), dim3(256), 0, stream, wt, qw, params);
    hipLaunchKernelGGL(gemm_i8_kernel,     dim3(2048), dim3(256), 0, stream,
                       qx, qw, inv_sx, params, bias, y);
}

// Round 8
// 719.936 us; speedup vs baseline: 1.1422x; 1.1422x over previous
//
#include <hip/hip_runtime.h>
#include <stdint.h>

// BitNet b1.58 column-parallel linear:
//   y[m,n] = (sum_k qx[m,k]*qw[n,k]) * inv_sx[m] * inv_sw + bias[n]
// M=8192 (B*S), N=16384 (D_OUT), K=4096 (D_IN)

#define M_ROWS 8192
#define N_COLS 16384
#define K_DIM  4096
#define NT     (K_DIM / 64)   // 64 K-steps of 64 bytes

typedef int v4i __attribute__((ext_vector_type(4)));

// ---------------- workspace layout ----------------
#define WS_PARTIALS 0
#define WS_PARAMS   8192
#define WS_INVSX    8448
#define WS_QX       41216
#define WS_QW       (41216 + 33554432)
#define WS_NEED     ((size_t)WS_QW + 67108864)

// ---------------- activation quant: per-row int8 absmax ----------------
__device__ __forceinline__ int quant_act1(float v, float s) {
    float q = rintf(v * s);               // round-half-even, matches jnp.round
    q = fminf(127.0f, fmaxf(-128.0f, q));
    return (int)q;
}

__global__ __launch_bounds__(256) void act_quant_kernel(const float* __restrict__ x,
                                                        int8_t* __restrict__ qx,
                                                        float* __restrict__ inv_sx) {
    const int row = blockIdx.x;
    const int t = threadIdx.x;
    const float4* xr = (const float4*)(x + (size_t)row * K_DIM);

    float4 v[4];
    float m = 0.0f;
#pragma unroll
    for (int i = 0; i < 4; ++i) {
        v[i] = xr[t + 256 * i];
        m = fmaxf(m, fmaxf(fmaxf(fabsf(v[i].x), fabsf(v[i].y)),
                           fmaxf(fabsf(v[i].z), fabsf(v[i].w))));
    }
#pragma unroll
    for (int off = 32; off > 0; off >>= 1) m = fmaxf(m, __shfl_xor(m, off));
    __shared__ float wm[4];
    if ((t & 63) == 0) wm[t >> 6] = m;
    __syncthreads();
    m = fmaxf(fmaxf(wm[0], wm[1]), fmaxf(wm[2], wm[3]));
    m = fmaxf(m, 1e-5f);                  // clip(max, EPS)
    const float scale = 127.0f / m;
    if (t == 0) inv_sx[row] = 1.0f / scale;

    int* qr = (int*)(qx + (size_t)row * K_DIM);
#pragma unroll
    for (int i = 0; i < 4; ++i) {
        int b0 = quant_act1(v[i].x, scale) & 255;
        int b1 = quant_act1(v[i].y, scale) & 255;
        int b2 = quant_act1(v[i].z, scale) & 255;
        int b3 = quant_act1(v[i].w, scale) & 255;
        qr[t + 256 * i] = b0 | (b1 << 8) | (b2 << 16) | (b3 << 24);
    }
}

// ---------------- weight abs-sum (deterministic two-stage) ----------------
__global__ __launch_bounds__(256) void wabs_partial_kernel(const float* __restrict__ w,
                                                           float* __restrict__ partials) {
    const int t = threadIdx.x;
    const size_t base = (size_t)blockIdx.x * 8192;   // float4 units
    const float4* w4 = (const float4*)w;
    float s = 0.0f;
#pragma unroll 8
    for (int i = 0; i < 32; ++i) {
        float4 v = w4[base + (size_t)i * 256 + t];
        s += fabsf(v.x) + fabsf(v.y) + fabsf(v.z) + fabsf(v.w);
    }
#pragma unroll
    for (int off = 32; off > 0; off >>= 1) s += __shfl_xor(s, off);
    __shared__ float wp[4];
    if ((t & 63) == 0) wp[t >> 6] = s;
    __syncthreads();
    if (t == 0) partials[blockIdx.x] = (wp[0] + wp[1]) + (wp[2] + wp[3]);
}

__global__ __launch_bounds__(256) void wfinal_kernel(const float* __restrict__ partials,
                                                     float* __restrict__ params) {
    __shared__ double sh[256];
    const int t = threadIdx.x;
    double s = 0.0;
    for (int i = t; i < 2048; i += 256) s += (double)partials[i];
    sh[t] = s;
    __syncthreads();
    for (int off = 128; off > 0; off >>= 1) {
        if (t < off) sh[t] += sh[t + off];
        __syncthreads();
    }
    if (t == 0) {
        float mean = (float)(sh[0] / 67108864.0);
        mean = fmaxf(mean, 1e-5f);        // clip(mean, EPS)
        float scale = 1.0f / mean;        // scale_w
        params[0] = scale;
        params[1] = 1.0f / scale;         // inv_sw
    }
}

// ---------------- weight quant: per-tensor ternary ----------------
__device__ __forceinline__ int quant_w1(float v, float s) {
    float q = rintf(v * s);
    q = fminf(1.0f, fmaxf(-1.0f, q));
    return (int)q;
}

__global__ __launch_bounds__(256) void w_quant_kernel(const float* __restrict__ w,
                                                      int8_t* __restrict__ qw,
                                                      const float* __restrict__ params) {
    const float scale = params[0];
    const int stride = gridDim.x * 256;
    const float4* w4 = (const float4*)w;
    int* q4 = (int*)qw;
    for (int g = blockIdx.x * 256 + threadIdx.x; g < 16777216; g += stride) {
        float4 v = w4[g];
        int b0 = quant_w1(v.x, scale) & 255;
        int b1 = quant_w1(v.y, scale) & 255;
        int b2 = quant_w1(v.z, scale) & 255;
        int b3 = quant_w1(v.w, scale) & 255;
        q4[g] = b0 | (b1 << 8) | (b2 << 16) | (b3 << 24);
    }
}

// ---------------- int8 GEMM: 256x256, 1 barrier/K-step, reads 1 step ahead, SGB interleave
// 8 waves (2M x 4N), per-wave 128x64, mfma_i32_16x16x64_i8 (verified layout).
// 4-slot ring (slot = ks&3), stage-3-ahead. Per step t:
//   { read aHi(t) from slot t + aLo/b(t+1) from slot t+1 + GLD4(t+3) + 32 MFMA(regs t),
//     all interleaved via sched_group_barrier {MFMA2,DS1}x12 {MFMA1,VMEM1}x4 {MFMA4};
//     vmcnt(4) [proves K(t+2)]; s_barrier [publishes slot t+2] }
// Read->MFMA reg deps are compiler-visible C loads -> auto counted lgkm waits; no manual
// lgkm. Slot-overwrite distance: reads of slot X complete ~120cy after issue; the GLD
// overwriting X issues >=1 full step (~1500cy) + ~300cy HBM latency later.
// 16B-chunk XOR swizzle on global source + ds_read addr (rounds 1-6: 0 conflicts).
__global__ __launch_bounds__(512, 2) void gemm_i8_kernel(const int8_t* __restrict__ qx,
                                                         const int8_t* __restrict__ qw,
                                                         const float* __restrict__ inv_sx,
                                                         const float* __restrict__ params,
                                                         const float* __restrict__ bias,
                                                         float* __restrict__ y) {
    __shared__ __align__(16) int8_t As[4][16384];
    __shared__ __align__(16) int8_t Bs[4][16384];
    int8_t* AsB = &As[0][0];
    int8_t* BsB = &Bs[0][0];

    const int tid = threadIdx.x;
    const int lane = tid & 63;
    const int w = tid >> 6;           // wave 0..7
    const int wr = w >> 2;            // 0..1  (M half)
    const int wc = w & 3;             // 0..3  (N quarter)
    const int wbase = w * 1024;       // wave-uniform LDS staging base (64 lanes x 16B)

    // XCD-aware bijective swizzle: 2048 blocks, 8 XCDs
    const int bid = blockIdx.x;
    const int swz = (bid & 7) * 256 + (bid >> 3);
    const int bn = swz & 63;          // 64 n-blocks
    const int bm = swz >> 6;          // 32 m-blocks

    const size_t arow0 = (size_t)bm * 256;
    const size_t brow0 = (size_t)bn * 256;

    // staging addressing: 512 chunks of 16B per 128-row half; thread tid -> chunk tid
    const int r0 = tid >> 2;                       // row 0..127 within half
    const int kc0 = (tid & 3) ^ ((r0 >> 1) & 3);   // swizzled k-slot (involution)
    const int8_t* gA0 = qx + (arow0 + r0) * K_DIM + kc0 * 16;
    const int8_t* gA1 = gA0 + (size_t)128 * K_DIM;
    const int8_t* gB0 = qw + (brow0 + r0) * K_DIM + kc0 * 16;
    const int8_t* gB1 = gB0 + (size_t)128 * K_DIM;

#define GLD(g, l)                                                                        \
    __builtin_amdgcn_global_load_lds((const __attribute__((address_space(1))) void*)(g), \
                                     (__attribute__((address_space(3))) void*)(l), 16, 0, 0)

#define GLD4(ks, SLOT)                                                                   \
    do {                                                                                 \
        const size_t _o = (size_t)(ks) * 64;                                             \
        GLD(gA0 + _o, AsB + (SLOT) * 16384 + wbase);                                     \
        GLD(gA1 + _o, AsB + (SLOT) * 16384 + 8192 + wbase);                              \
        GLD(gB0 + _o, BsB + (SLOT) * 16384 + wbase);                                     \
        GLD(gB1 + _o, BsB + (SLOT) * 16384 + 8192 + wbase);                              \
    } while (0)

    // fragment ds_read offsets (within one 16KB slot) — verified 16x16x64 layout
    const int ksub = lane >> 4;       // 16B k-chunk 0..3
    const int lrow = lane & 15;
    int aoff[8], boff[4];
#pragma unroll
    for (int i = 0; i < 8; ++i) {
        int ra = wr * 128 + i * 16 + lrow;
        aoff[i] = ra * 64 + ((ksub ^ ((ra >> 1) & 3)) << 4);
    }
#pragma unroll
    for (int j = 0; j < 4; ++j) {
        int rb = wc * 64 + j * 16 + lrow;
        boff[j] = rb * 64 + ((ksub ^ ((rb >> 1) & 3)) << 4);
    }

    v4i acc[8][4];
#pragma unroll
    for (int i = 0; i < 8; ++i)
#pragma unroll
        for (int j = 0; j < 4; ++j) acc[i][j] = (v4i){0, 0, 0, 0};

    // fragment registers: aLo/b double-buffered (1 step ahead), aHi same-step
    v4i aLoE[4], aLoO[4], bE[4], bO[4], aH[4];

#define BARR()                                                                 \
    do {                                                                       \
        __builtin_amdgcn_s_barrier();                                          \
        __builtin_amdgcn_sched_barrier(0);                                     \
    } while (0)
#define VM8() asm volatile("s_waitcnt vmcnt(8)" ::: "memory")
#define VM4() asm volatile("s_waitcnt vmcnt(4)" ::: "memory")
#define VM0() asm volatile("s_waitcnt vmcnt(0)" ::: "memory")
#define SGB(m, n) __builtin_amdgcn_sched_group_barrier((m), (n), 0)

// per-step interleave: 32 MFMA, 12 DS_READ, 4 VMEM_READ
#define PATTERN()                                                              \
    do {                                                                       \
        _Pragma("unroll") for (int _k = 0; _k < 12; ++_k) {                    \
            SGB(0x8, 2);                                                       \
            SGB(0x100, 1);                                                     \
        }                                                                      \
        _Pragma("unroll") for (int _k = 0; _k < 4; ++_k) {                     \
            SGB(0x8, 1);                                                       \
            SGB(0x20, 1);                                                      \
        }                                                                      \
        SGB(0x8, 4);                                                           \
    } while (0)

// One K-step t: consume {AL,BL} = regs(t) (+ aH read now from slot S=t&3),
// prefetch {ALN,BLN} = regs(t+1) from slot NS, stage K-step FKS (if STG).
#define STEP(AL, BL, ALN, BLN, S, NS, FKS, DONXT, STG, VMSTMT, DOBAR, DOPAT)   \
    do {                                                                       \
        _Pragma("unroll") for (int _i = 0; _i < 4; ++_i)                       \
            aH[_i] = *(const v4i*)(AsB + (S) * 16384 + aoff[4 + _i]);          \
        if (DONXT) {                                                           \
            _Pragma("unroll") for (int _i = 0; _i < 4; ++_i)                   \
                ALN[_i] = *(const v4i*)(AsB + (NS) * 16384 + aoff[_i]);        \
            _Pragma("unroll") for (int _j = 0; _j < 4; ++_j)                   \
                BLN[_j] = *(const v4i*)(BsB + (NS) * 16384 + boff[_j]);        \
        }                                                                      \
        if (STG) GLD4((FKS), (FKS) & 3);                                       \
        _Pragma("unroll") for (int _i = 0; _i < 4; ++_i)                       \
            _Pragma("unroll") for (int _j = 0; _j < 4; ++_j)                   \
                acc[_i][_j] = __builtin_amdgcn_mfma_i32_16x16x64_i8(           \
                    AL[_i], BL[_j], acc[_i][_j], 0, 0, 0);                     \
        _Pragma("unroll") for (int _i = 0; _i < 4; ++_i)                       \
            _Pragma("unroll") for (int _j = 0; _j < 4; ++_j)                   \
                acc[4 + _i][_j] = __builtin_amdgcn_mfma_i32_16x16x64_i8(       \
                    aH[_i], BL[_j], acc[4 + _i][_j], 0, 0, 0);                 \
        if (DOPAT) PATTERN();                                                  \
        VMSTMT;                                                                \
        if (DOBAR) BARR();                                                     \
    } while (0)

    // prologue: stage K0,K1,K2; publish slot 0; preload regs(0); publish slot 1
    GLD4(0, 0);
    GLD4(1, 1);
    GLD4(2, 2);
    VM8();                 // K0 landed (K1,K2 outstanding = 8)
    BARR();                // publish slot 0
#pragma unroll
    for (int i = 0; i < 4; ++i) aLoE[i] = *(const v4i*)(AsB + aoff[i]);
#pragma unroll
    for (int j = 0; j < 4; ++j) bE[j] = *(const v4i*)(BsB + boff[j]);
    VM4();                 // K1 landed (K2 outstanding = 4)
    BARR();                // publish slot 1

    // main loop: t = 4j..4j+3 (j=0..14 -> t=0..59), staging t+3 (<=62)
#pragma unroll 1
    for (int j = 0; j < 15; ++j) {
        const int tb = 4 * j;
        STEP(aLoE, bE, aLoO, bO, 0, 1, tb + 3, 1, 1, VM4(), 1, 1);
        STEP(aLoO, bO, aLoE, bE, 1, 2, tb + 4, 1, 1, VM4(), 1, 1);
        STEP(aLoE, bE, aLoO, bO, 2, 3, tb + 5, 1, 1, VM4(), 1, 1);
        STEP(aLoO, bO, aLoE, bE, 3, 0, tb + 6, 1, 1, VM4(), 1, 1);
    }
    // tail: t=60 stages K63; vmcnt drains 4 -> 0 -> none
    STEP(aLoE, bE, aLoO, bO, 0, 1, 63, 1, 1, VM4(), 1, 0);   // t=60: proves K62
    STEP(aLoO, bO, aLoE, bE, 1, 2, 0, 1, 0, VM0(), 1, 0);    // t=61: proves K63
    STEP(aLoE, bE, aLoO, bO, 2, 3, 0, 1, 0, (void)0, 0, 0);  // t=62
    STEP(aLoO, bO, aLoE, bE, 3, 0, 0, 0, 0, (void)0, 0, 0);  // t=63

    // epilogue: y = acc * inv_sx[row] * inv_sw + bias[col]  (verified 16x16 C/D layout)
    const float invsw = params[1];
    const int rl = (lane >> 4) * 4;
#pragma unroll
    for (int i = 0; i < 8; ++i) {
        const int grow_base = (int)arow0 + wr * 128 + i * 16 + rl;
        float isx[4];
#pragma unroll
        for (int r = 0; r < 4; ++r) isx[r] = inv_sx[grow_base + r] * invsw;
#pragma unroll
        for (int j = 0; j < 4; ++j) {
            const int gcol = (int)brow0 + wc * 64 + j * 16 + lrow;
            const float bb = bias[gcol];
#pragma unroll
            for (int r = 0; r < 4; ++r) {
                y[(size_t)(grow_base + r) * N_COLS + gcol] =
                    (float)acc[i][j][r] * isx[r] + bb;
            }
        }
    }
#undef GLD
#undef GLD4
#undef BARR
#undef VM8
#undef VM4
#undef VM0
#undef SGB
#undef PATTERN
#undef STEP
}

// ---------------- launch ----------------
extern "C" void kernel_launch(void* const* d_in, const int* in_sizes, int n_in,
                              void* d_out, int out_size, void* d_ws, size_t ws_size,
                              hipStream_t stream) {
    const float* x    = (const float*)d_in[0];
    const float* wt   = (const float*)d_in[1];
    const float* bias = (const float*)d_in[2];
    float* y = (float*)d_out;

    if (ws_size < WS_NEED) return;

    char* ws = (char*)d_ws;
    float* partials = (float*)(ws + WS_PARTIALS);
    float* params   = (float*)(ws + WS_PARAMS);
    float* inv_sx   = (float*)(ws + WS_INVSX);
    int8_t* qx = (int8_t*)(ws + WS_QX);
    int8_t* qw = (int8_t*)(ws + WS_QW);

    hipLaunchKernelGGL(act_quant_kernel,   dim3(8192), dim3(256), 0, stream, x, qx, inv_sx);
    hipLaunchKernelGGL(wabs_partial_kernel,dim3(2048), dim3(256), 0, stream, wt, partials);
    hipLaunchKernelGGL(wfinal_kernel,      dim3(1),    dim3(256), 0, stream, partials, params);
    hipLaunchKernelGGL(w_quant_kernel,     dim3(4096), dim3(256), 0, stream, wt, qw, params);
    hipLaunchKernelGGL(gemm_i8_kernel,     dim3(2048), dim3(512), 0, stream,
                       qx, qw, inv_sx, params, bias, y);
}

// Round 9
// 708.752 us; speedup vs baseline: 1.1602x; 1.0158x over previous
//
#include <hip/hip_runtime.h>
#include <stdint.h>

// BitNet b1.58 column-parallel linear:
//   y[m,n] = (sum_k qx[m,k]*qw[n,k]) * inv_sx[m] * inv_sw + bias[n]
// M=8192 (B*S), N=16384 (D_OUT), K=4096 (D_IN)

#define M_ROWS 8192
#define N_COLS 16384
#define K_DIM  4096
#define NT     (K_DIM / 64)   // 64 K-steps of 64 bytes

typedef int v4i __attribute__((ext_vector_type(4)));

// ---------------- workspace layout ----------------
#define WS_PARTIALS 0
#define WS_PARAMS   8192
#define WS_INVSX    8448
#define WS_QX       41216
#define WS_QW       (41216 + 33554432)
#define WS_NEED     ((size_t)WS_QW + 67108864)

// ---------------- activation quant: per-row int8 absmax ----------------
__device__ __forceinline__ int quant_act1(float v, float s) {
    float q = rintf(v * s);               // round-half-even, matches jnp.round
    q = fminf(127.0f, fmaxf(-128.0f, q));
    return (int)q;
}

__global__ __launch_bounds__(256) void act_quant_kernel(const float* __restrict__ x,
                                                        int8_t* __restrict__ qx,
                                                        float* __restrict__ inv_sx) {
    const int row = blockIdx.x;
    const int t = threadIdx.x;
    const float4* xr = (const float4*)(x + (size_t)row * K_DIM);

    float4 v[4];
    float m = 0.0f;
#pragma unroll
    for (int i = 0; i < 4; ++i) {
        v[i] = xr[t + 256 * i];
        m = fmaxf(m, fmaxf(fmaxf(fabsf(v[i].x), fabsf(v[i].y)),
                           fmaxf(fabsf(v[i].z), fabsf(v[i].w))));
    }
#pragma unroll
    for (int off = 32; off > 0; off >>= 1) m = fmaxf(m, __shfl_xor(m, off));
    __shared__ float wm[4];
    if ((t & 63) == 0) wm[t >> 6] = m;
    __syncthreads();
    m = fmaxf(fmaxf(wm[0], wm[1]), fmaxf(wm[2], wm[3]));
    m = fmaxf(m, 1e-5f);                  // clip(max, EPS)
    const float scale = 127.0f / m;
    if (t == 0) inv_sx[row] = 1.0f / scale;

    int* qr = (int*)(qx + (size_t)row * K_DIM);
#pragma unroll
    for (int i = 0; i < 4; ++i) {
        int b0 = quant_act1(v[i].x, scale) & 255;
        int b1 = quant_act1(v[i].y, scale) & 255;
        int b2 = quant_act1(v[i].z, scale) & 255;
        int b3 = quant_act1(v[i].w, scale) & 255;
        qr[t + 256 * i] = b0 | (b1 << 8) | (b2 << 16) | (b3 << 24);
    }
}

// ---------------- weight abs-sum (deterministic two-stage) ----------------
__global__ __launch_bounds__(256) void wabs_partial_kernel(const float* __restrict__ w,
                                                           float* __restrict__ partials) {
    const int t = threadIdx.x;
    const size_t base = (size_t)blockIdx.x * 8192;   // float4 units
    const float4* w4 = (const float4*)w;
    float s = 0.0f;
#pragma unroll 8
    for (int i = 0; i < 32; ++i) {
        float4 v = w4[base + (size_t)i * 256 + t];
        s += fabsf(v.x) + fabsf(v.y) + fabsf(v.z) + fabsf(v.w);
    }
#pragma unroll
    for (int off = 32; off > 0; off >>= 1) s += __shfl_xor(s, off);
    __shared__ float wp[4];
    if ((t & 63) == 0) wp[t >> 6] = s;
    __syncthreads();
    if (t == 0) partials[blockIdx.x] = (wp[0] + wp[1]) + (wp[2] + wp[3]);
}

__global__ __launch_bounds__(256) void wfinal_kernel(const float* __restrict__ partials,
                                                     float* __restrict__ params) {
    __shared__ double sh[256];
    const int t = threadIdx.x;
    double s = 0.0;
    for (int i = t; i < 2048; i += 256) s += (double)partials[i];
    sh[t] = s;
    __syncthreads();
    for (int off = 128; off > 0; off >>= 1) {
        if (t < off) sh[t] += sh[t + off];
        __syncthreads();
    }
    if (t == 0) {
        float mean = (float)(sh[0] / 67108864.0);
        mean = fmaxf(mean, 1e-5f);        // clip(mean, EPS)
        float scale = 1.0f / mean;        // scale_w
        params[0] = scale;
        params[1] = 1.0f / scale;         // inv_sw
    }
}

// ---------------- weight quant: per-tensor ternary ----------------
__device__ __forceinline__ int quant_w1(float v, float s) {
    float q = rintf(v * s);
    q = fminf(1.0f, fmaxf(-1.0f, q));
    return (int)q;
}

__global__ __launch_bounds__(256) void w_quant_kernel(const float* __restrict__ w,
                                                      int8_t* __restrict__ qw,
                                                      const float* __restrict__ params) {
    const float scale = params[0];
    const int stride = gridDim.x * 256;
    const float4* w4 = (const float4*)w;
    int* q4 = (int*)qw;
    for (int g = blockIdx.x * 256 + threadIdx.x; g < 16777216; g += stride) {
        float4 v = w4[g];
        int b0 = quant_w1(v.x, scale) & 255;
        int b1 = quant_w1(v.y, scale) & 255;
        int b2 = quant_w1(v.z, scale) & 255;
        int b3 = quant_w1(v.w, scale) & 255;
        q4[g] = b0 | (b1 << 8) | (b2 << 16) | (b3 << 24);
    }
}

// ---------------- int8 GEMM: 256x128 tile, 4 waves, 3-slot ring, 2 BLOCKS/CU ----
// m114 mechanism: two independent co-resident blocks per CU (LDS 72KB x 2 <= 160KB,
// regs <= 256/wave incl AGPR via launch_bounds(256,2)) provide MFMA<->LDS overlap —
// when one block's waves are in their read/barrier phase, the other block's waves
// feed the MFMA pipe. Per block-step: MFMA 653 SIMD-cy vs LDS 72KB (~600-850 cy);
// per-CU pair ~1306 MFMA-bound with overlap.
// 4 waves (2M x 2N), per-wave 128x64, mfma_i32_16x16x64_i8 (verified layout).
// 3-slot ring (slot = t%3), stage-2-ahead, 6 GLD/thread/step (4 A + 2 B).
// Per step t: { 12 ds_read slot t%3 | GLD6(t+2 -> (t+2)%3) | 32 MFMA |
//              vmcnt(6) [proves K(t+1)] | s_barrier [publishes slot (t+1)%3] }.
// Slot-overwrite safety: GLD(t+2) targets slot (t-1)%3 whose reads drained before the
// end-of-(t-1) barrier (MFMA reg deps force lgkm completion pre-barrier).
// 16B-chunk XOR swizzle on global source + ds_read addr (rounds 1-8: 0 conflicts);
// row-stride-64 staging keeps the XOR term invariant ((row>>1)&3 unchanged mod 64).
__global__ __launch_bounds__(256, 2) void gemm_i8_kernel(const int8_t* __restrict__ qx,
                                                         const int8_t* __restrict__ qw,
                                                         const float* __restrict__ inv_sx,
                                                         const float* __restrict__ params,
                                                         const float* __restrict__ bias,
                                                         float* __restrict__ y) {
    __shared__ __align__(16) int8_t lds[3][24576];   // per slot: A[256][64] + B[128][64]
    int8_t* L = &lds[0][0];

    const int tid = threadIdx.x;
    const int lane = tid & 63;
    const int w = tid >> 6;           // wave 0..3
    const int wr = w >> 1;            // 0..1  (M half)
    const int wc = w & 1;             // 0..1  (N half)
    const int wbase = w * 1024;       // wave-uniform LDS staging base (64 lanes x 16B)

    // XCD-aware bijective swizzle: 4096 blocks, 8 XCDs
    const int bid = blockIdx.x;
    const int swz = (bid & 7) * 512 + (bid >> 3);
    const int bn = swz & 127;         // 128 n-blocks (fast: consecutive share A-panel)
    const int bm = swz >> 7;          // 32 m-blocks

    const size_t arow0 = (size_t)bm * 256;
    const size_t bcol0 = (size_t)bn * 128;

    // staging: A 1024 chunks (4/thread, row stride 64), B 512 chunks (2/thread)
    const int r0 = tid >> 2;                       // 0..63
    const int kc0 = (tid & 3) ^ ((r0 >> 1) & 3);   // swizzled k-slot (involution)
    const int8_t* gA = qx + (arow0 + r0) * K_DIM + kc0 * 16;
    const int8_t* gB = qw + (bcol0 + r0) * K_DIM + kc0 * 16;

#define GLD(g, l)                                                                        \
    __builtin_amdgcn_global_load_lds((const __attribute__((address_space(1))) void*)(g), \
                                     (__attribute__((address_space(3))) void*)(l), 16, 0, 0)

// stage K-step ks into slot S: 4 A chunks + 2 B chunks per thread
#define GLD6(ks, S)                                                                      \
    do {                                                                                 \
        const size_t _o = (size_t)(ks) * 64;                                             \
        _Pragma("unroll") for (int _g = 0; _g < 4; ++_g)                                 \
            GLD(gA + _o + (size_t)_g * (64 * K_DIM),                                     \
                L + (S) * 24576 + _g * 4096 + wbase);                                    \
        _Pragma("unroll") for (int _h = 0; _h < 2; ++_h)                                 \
            GLD(gB + _o + (size_t)_h * (64 * K_DIM),                                     \
                L + (S) * 24576 + 16384 + _h * 4096 + wbase);                            \
    } while (0)

    // fragment ds_read offsets (within one 24KB slot) — verified 16x16x64 layout
    const int ksub = lane >> 4;       // 16B k-chunk 0..3
    const int lrow = lane & 15;
    int aoff[8], boff[4];
#pragma unroll
    for (int i = 0; i < 8; ++i) {
        int ra = wr * 128 + i * 16 + lrow;
        aoff[i] = ra * 64 + ((ksub ^ ((ra >> 1) & 3)) << 4);
    }
#pragma unroll
    for (int j = 0; j < 4; ++j) {
        int rb = wc * 64 + j * 16 + lrow;
        boff[j] = 16384 + rb * 64 + ((ksub ^ ((rb >> 1) & 3)) << 4);
    }

    v4i acc[8][4];
#pragma unroll
    for (int i = 0; i < 8; ++i)
#pragma unroll
        for (int j = 0; j < 4; ++j) acc[i][j] = (v4i){0, 0, 0, 0};

#define BARR()                                                                 \
    do {                                                                       \
        __builtin_amdgcn_s_barrier();                                          \
        __builtin_amdgcn_sched_barrier(0);                                     \
    } while (0)
#define VM(NSTR) asm volatile("s_waitcnt vmcnt(" NSTR ")" ::: "memory")

// One K-step: read 12 frags from slot CS, stage FKS (if STG), 32 MFMA, wait, barrier.
#define STEP(CS, FKS, FSL, STG, VMSTMT, DOBAR)                                 \
    do {                                                                       \
        const int8_t* _p = L + (CS) * 24576;                                   \
        v4i a[8], b[4];                                                        \
        _Pragma("unroll") for (int _i = 0; _i < 8; ++_i)                       \
            a[_i] = *(const v4i*)(_p + aoff[_i]);                              \
        _Pragma("unroll") for (int _j = 0; _j < 4; ++_j)                       \
            b[_j] = *(const v4i*)(_p + boff[_j]);                              \
        if (STG) GLD6(FKS, FSL);                                               \
        __builtin_amdgcn_s_setprio(1);                                         \
        _Pragma("unroll") for (int _i = 0; _i < 8; ++_i)                       \
            _Pragma("unroll") for (int _j = 0; _j < 4; ++_j)                   \
                acc[_i][_j] = __builtin_amdgcn_mfma_i32_16x16x64_i8(           \
                    a[_i], b[_j], acc[_i][_j], 0, 0, 0);                       \
        __builtin_amdgcn_s_setprio(0);                                         \
        VMSTMT;                                                                \
        if (DOBAR) BARR();                                                     \
    } while (0)

    // prologue: stage K0->s0, K1->s1; vmcnt(6) proves K0; barrier publishes s0
    GLD6(0, 0);
    GLD6(1, 1);
    VM("6");
    BARR();

    // main loop: j=0..19, K-steps 3j..3j+2 (t=0..59), staging t+2 (slots 2,0,1)
#pragma unroll 1
    for (int j = 0; j < 20; ++j) {
        const int tb = 3 * j;
        STEP(0, tb + 2, 2, 1, VM("6"), 1);   // t=3j:   proves K(t+1)
        STEP(1, tb + 3, 0, 1, VM("6"), 1);
        STEP(2, tb + 4, 1, 1, VM("6"), 1);
    }
    // tail: t=60..63 (slots 0,1,2,0); K62 staged at t=60, K63 at t=61
    STEP(0, 62, 2, 1, VM("6"), 1);     // t=60: proves K61
    STEP(1, 63, 0, 1, VM("6"), 1);     // t=61: proves K62
    STEP(2, 0, 0, 0, VM("0"), 1);      // t=62: proves K63
    STEP(0, 0, 0, 0, (void)0, 0);      // t=63

    // epilogue: y = acc * inv_sx[row] * inv_sw + bias[col]  (verified 16x16 C/D layout)
    const float invsw = params[1];
    const int rl = (lane >> 4) * 4;
#pragma unroll
    for (int i = 0; i < 8; ++i) {
        const int grow_base = (int)arow0 + wr * 128 + i * 16 + rl;
        float isx[4];
#pragma unroll
        for (int r = 0; r < 4; ++r) isx[r] = inv_sx[grow_base + r] * invsw;
#pragma unroll
        for (int j = 0; j < 4; ++j) {
            const int gcol = (int)bcol0 + wc * 64 + j * 16 + lrow;
            const float bb = bias[gcol];
#pragma unroll
            for (int r = 0; r < 4; ++r) {
                y[(size_t)(grow_base + r) * N_COLS + gcol] =
                    (float)acc[i][j][r] * isx[r] + bb;
            }
        }
    }
#undef GLD
#undef GLD6
#undef BARR
#undef VM
#undef STEP
}

// ---------------- launch ----------------
extern "C" void kernel_launch(void* const* d_in, const int* in_sizes, int n_in,
                              void* d_out, int out_size, void* d_ws, size_t ws_size,
                              hipStream_t stream) {
    const float* x    = (const float*)d_in[0];
    const float* wt   = (const float*)d_in[1];
    const float* bias = (const float*)d_in[2];
    float* y = (float*)d_out;

    if (ws_size < WS_NEED) return;

    char* ws = (char*)d_ws;
    float* partials = (float*)(ws + WS_PARTIALS);
    float* params   = (float*)(ws + WS_PARAMS);
    float* inv_sx   = (float*)(ws + WS_INVSX);
    int8_t* qx = (int8_t*)(ws + WS_QX);
    int8_t* qw = (int8_t*)(ws + WS_QW);

    hipLaunchKernelGGL(act_quant_kernel,   dim3(8192), dim3(256), 0, stream, x, qx, inv_sx);
    hipLaunchKernelGGL(wabs_partial_kernel,dim3(2048), dim3(256), 0, stream, wt, partials);
    hipLaunchKernelGGL(wfinal_kernel,      dim3(1),    dim3(256), 0, stream, partials, params);
    hipLaunchKernelGGL(w_quant_kernel,     dim3(4096), dim3(256), 0, stream, wt, qw, params);
    hipLaunchKernelGGL(gemm_i8_kernel,     dim3(4096), dim3(256), 0, stream,
                       qx, qw, inv_sx, params, bias, y);
}